// Round 6
// baseline (343.764 us; speedup 1.0000x reference)
//
#include <hip/hip_runtime.h>
#include <math.h>

#define NDIM 64

__device__ __forceinline__ unsigned bf16rne(unsigned u) {
    return (u + 0x7fffu + ((u >> 16) & 1u)) >> 16;
}

// ---------- nodeprep (tier A): wave per node -> h16 row + s12 scalars ----------
__global__ void __launch_bounds__(256)
k_nodeprep(const float* __restrict__ h,
           const float* __restrict__ pw, const float* __restrict__ nw,
           unsigned short* __restrict__ h16, float2* __restrict__ s12, int n_nodes) {
    const int lane = threadIdx.x & 63;
    const int n = blockIdx.x * 4 + (threadIdx.x >> 6);
    if (n >= n_nodes) return;
    const float a = h[(size_t)n * NDIM + lane];
    const float pa = fmaxf(a, 0.f), na = pa - a;
    float t1 = pa * pw[lane]      - na * nw[lane];
    float t2 = pa * pw[64 + lane] - na * nw[64 + lane];
    #pragma unroll
    for (int m = 32; m >= 1; m >>= 1) {
        t1 += __shfl_xor(t1, m, 64);
        t2 += __shfl_xor(t2, m, 64);
    }
    h16[(size_t)n * NDIM + lane] = (unsigned short)bf16rne(__float_as_uint(a));
    if (lane == 0) s12[n] = make_float2(t1, t2);
}

// ---------- k00 (tier B): h f32 -> bf16 ----------
__global__ void __launch_bounds__(256)
k00_cvt(const float* __restrict__ h, unsigned int* __restrict__ h16, int n4) {
    const int i = blockIdx.x * 256 + threadIdx.x;
    if (i >= n4) return;
    const float4 f = ((const float4*)h)[i];
    unsigned bx = bf16rne(__float_as_uint(f.x)), by = bf16rne(__float_as_uint(f.y));
    unsigned bz = bf16rne(__float_as_uint(f.z)), bw = bf16rne(__float_as_uint(f.w));
    ((uint2*)h16)[i] = make_uint2(bx | (by << 16), bz | (bw << 16));
}

// ---------- k0b (tier A): compact packed (vi|vj<<16) + vj histogram ----------
__global__ void __launch_bounds__(256)
k0b_pack(const int* __restrict__ edges, unsigned* __restrict__ pvivj,
         int* __restrict__ hist, int n_edges) {
    const int e = blockIdx.x * 256 + threadIdx.x;
    if (e >= n_edges) return;
    const int vi = edges[e * 8 + 1];
    const int vj = edges[e * 8 + 2];
    pvivj[e] = (unsigned)vi | ((unsigned)vj << 16);
    atomicAdd(&hist[vj], 1);
}

// ---------- k1 (tier A): folded math on packed edges ----------
__global__ void __launch_bounds__(256)
k1_fold(const unsigned* __restrict__ pvivj,
        const unsigned short* __restrict__ h16,
        const float2* __restrict__ s12,
        const float* __restrict__ w2p, const float* __restrict__ w2n,
        float* __restrict__ ex, int n_edges) {
    const int e = blockIdx.x * 256 + threadIdx.x;
    if (e >= n_edges) return;
    const unsigned v = pvivj[e];
    const int vi = (int)(v & 0xffffu), vj = (int)(v >> 16);
    const uint4* hi = (const uint4*)(h16 + (size_t)vi * NDIM);
    const uint4* hj = (const uint4*)(h16 + (size_t)vj * NDIM);
    float cp = 0.f, cn = 0.f;
    #pragma unroll
    for (int q = 0; q < 8; ++q) {
        const uint4 ua = hi[q];
        const uint4 ub = hj[q];
        const unsigned au[4] = {ua.x, ua.y, ua.z, ua.w};
        const unsigned bu[4] = {ub.x, ub.y, ub.z, ub.w};
        #pragma unroll
        for (int k = 0; k < 4; ++k) {
            const int d = q * 8 + k * 2;
            const float a0 = __uint_as_float(au[k] << 16);
            const float a1 = __uint_as_float(au[k] & 0xffff0000u);
            const float b0 = __uint_as_float(bu[k] << 16);
            const float b1 = __uint_as_float(bu[k] & 0xffff0000u);
            const float pa0 = fmaxf(a0, 0.f), na0 = pa0 - a0;
            const float pb0 = fmaxf(b0, 0.f), nb0 = pb0 - b0;
            const float pa1 = fmaxf(a1, 0.f), na1 = pa1 - a1;
            const float pb1 = fmaxf(b1, 0.f), nb1 = pb1 - b1;
            cp = fmaf(pa0 * pb0, w2p[d],     cp);
            cn = fmaf(na0 * nb0, w2n[d],     cn);
            cp = fmaf(pa1 * pb1, w2p[d + 1], cp);
            cn = fmaf(na1 * nb1, w2n[d + 1], cn);
        }
    }
    const float2 si = s12[vi];
    const float2 sj = s12[vj];
    ex[e] = __expf(si.x + sj.y + cp - cn);
}

__device__ __forceinline__ float edge_term(float a, float b,
                                           float w0, float w1, float w2,
                                           float w3, float w4, float w5) {
    const float pa = fmaxf(a, 0.f), na = pa - a;
    const float pb = fmaxf(b, 0.f), nb = pb - b;
    return pa * w0 + pb * w1 + (pa * pb) * w2
         - (na * w3 + nb * w4 + (na * nb) * w5);
}

// ---------- k1 (tier B/C): full math reading stride-8 edge table ----------
template <bool BF16>
__global__ void __launch_bounds__(256)
k1_full(const int* __restrict__ edges,
        const void* __restrict__ hptr,
        const float* __restrict__ pw,
        const float* __restrict__ nw,
        float* __restrict__ ex,
        int* __restrict__ hist,
        int n_edges) {
    const int e = blockIdx.x * 256 + threadIdx.x;
    if (e >= n_edges) return;
    const int vi = edges[e * 8 + 1];
    const int vj = edges[e * 8 + 2];
    float c = 0.f;
    if (BF16) {
        const unsigned short* h16 = (const unsigned short*)hptr;
        const uint4* hi = (const uint4*)(h16 + (size_t)vi * NDIM);
        const uint4* hj = (const uint4*)(h16 + (size_t)vj * NDIM);
        #pragma unroll 4
        for (int q = 0; q < 8; ++q) {
            const uint4 ua = hi[q];
            const uint4 ub = hj[q];
            const unsigned au[4] = {ua.x, ua.y, ua.z, ua.w};
            const unsigned bu[4] = {ub.x, ub.y, ub.z, ub.w};
            #pragma unroll
            for (int k = 0; k < 4; ++k) {
                const int d = q * 8 + k * 2;
                const float a0 = __uint_as_float(au[k] << 16);
                const float a1 = __uint_as_float(au[k] & 0xffff0000u);
                const float b0 = __uint_as_float(bu[k] << 16);
                const float b1 = __uint_as_float(bu[k] & 0xffff0000u);
                c += edge_term(a0, b0, pw[d], pw[64 + d], pw[128 + d],
                                       nw[d], nw[64 + d], nw[128 + d]);
                c += edge_term(a1, b1, pw[d + 1], pw[64 + d + 1], pw[128 + d + 1],
                                       nw[d + 1], nw[64 + d + 1], nw[128 + d + 1]);
            }
        }
    } else {
        const float* h = (const float*)hptr;
        const float4* hi = (const float4*)(h + (size_t)vi * NDIM);
        const float4* hj = (const float4*)(h + (size_t)vj * NDIM);
        #pragma unroll 4
        for (int q = 0; q < 16; ++q) {
            const float4 a = hi[q];
            const float4 b = hj[q];
            const int d = q * 4;
            c += edge_term(a.x, b.x, pw[d],     pw[64 + d],     pw[128 + d],
                                     nw[d],     nw[64 + d],     nw[128 + d]);
            c += edge_term(a.y, b.y, pw[d + 1], pw[64 + d + 1], pw[128 + d + 1],
                                     nw[d + 1], nw[64 + d + 1], nw[128 + d + 1]);
            c += edge_term(a.z, b.z, pw[d + 2], pw[64 + d + 2], pw[128 + d + 2],
                                     nw[d + 2], nw[64 + d + 2], nw[128 + d + 2]);
            c += edge_term(a.w, b.w, pw[d + 3], pw[64 + d + 3], pw[128 + d + 3],
                                     nw[d + 3], nw[64 + d + 3], nw[128 + d + 3]);
        }
    }
    ex[e] = __expf(c);
    atomicAdd(&hist[vj], 1);
}

// ---------- k2: thread per node, binary search sorted vi, rdenom ----------
template <bool PACKED>
__global__ void __launch_bounds__(256)
k2_denom(const void* __restrict__ viptr, int stride,
         const float* __restrict__ ex, float* __restrict__ rdenom,
         int n_edges, int n_nodes) {
    const int n = blockIdx.x * 256 + threadIdx.x;
    if (n >= n_nodes) return;
    const unsigned* pv = (const unsigned*)viptr;
    const int* va = (const int*)viptr;
    int lo = 0, hi = n_edges;
    while (lo < hi) {
        int mid = (lo + hi) >> 1;
        int v = PACKED ? (int)(pv[mid] & 0xffffu) : va[(size_t)mid * stride];
        if (v < n) lo = mid + 1; else hi = mid;
    }
    const int beg = lo;
    hi = n_edges;
    while (lo < hi) {
        int mid = (lo + hi) >> 1;
        int v = PACKED ? (int)(pv[mid] & 0xffffu) : va[(size_t)mid * stride];
        if (v < n + 1) lo = mid + 1; else hi = mid;
    }
    const int end = lo;
    float s = 0.f;
    for (int e = beg; e < end; ++e) s += ex[e];
    rdenom[n] = (end > beg) ? 1.f / s : 0.f;
}

// ---------- exclusive scan over hist ----------
__global__ void __launch_bounds__(256)
scan_blocks(int* __restrict__ data, int* __restrict__ bsum, int n) {
    __shared__ int sm[256];
    const int t = threadIdx.x;
    const int i = blockIdx.x * 256 + t;
    int v = (i < n) ? data[i] : 0;
    sm[t] = v;
    __syncthreads();
    int x = v;
    #pragma unroll
    for (int off = 1; off < 256; off <<= 1) {
        int add = (t >= off) ? sm[t - off] : 0;
        __syncthreads();
        x += add; sm[t] = x;
        __syncthreads();
    }
    if (i < n) data[i] = x - v;
    if (t == 255) bsum[blockIdx.x] = x;
}

__global__ void __launch_bounds__(256)
scan_top(int* __restrict__ bsum, int nb) {
    __shared__ int sm[256];
    const int t = threadIdx.x;
    int v = (t < nb) ? bsum[t] : 0;
    sm[t] = v;
    __syncthreads();
    int x = v;
    #pragma unroll
    for (int off = 1; off < 256; off <<= 1) {
        int add = (t >= off) ? sm[t - off] : 0;
        __syncthreads();
        x += add; sm[t] = x;
        __syncthreads();
    }
    if (t < nb) bsum[t] = x - v;
}

__global__ void __launch_bounds__(256)
scan_add(int* __restrict__ data, const int* __restrict__ bsum, int n, int total) {
    const int i = blockIdx.x * 256 + threadIdx.x;
    if (i < n) data[i] += bsum[blockIdx.x];
    else if (i == n) data[i] = total;
}

// ---------- k3a: scatter to vj-sorted slots; atomic directly on offs ----------
template <bool PACKED>
__global__ void __launch_bounds__(256)
k3a_scatter(const void* __restrict__ viptr, int stride,
            const float* __restrict__ ex, const float* __restrict__ rdenom,
            int* __restrict__ offs, int2* __restrict__ rec, int n_edges) {
    const int e = blockIdx.x * 256 + threadIdx.x;
    if (e >= n_edges) return;
    int vi, vj;
    if (PACKED) {
        const unsigned v = ((const unsigned*)viptr)[e];
        vi = (int)(v & 0xffffu); vj = (int)(v >> 16);
    } else {
        const int* va = (const int*)viptr;
        vi = va[(size_t)e * stride]; vj = va[(size_t)e * stride + 1];
    }
    const float attn = ex[e] * rdenom[vi];
    const int pos = atomicAdd(&offs[vj], 1);
    rec[pos] = make_int2(vi, __float_as_int(attn));
}

// ---------- k3b: wave per node; post-k3a offs: beg=offs[n-1], end=offs[n] ----------
template <bool BF16>
__global__ void __launch_bounds__(256)
k3b_gather(const int2* __restrict__ rec, const int* __restrict__ offs,
           const void* __restrict__ hptr, float* __restrict__ out, int n_nodes) {
    const int lane = threadIdx.x & 63;
    const int n = blockIdx.x * 4 + (threadIdx.x >> 6);
    if (n >= n_nodes) return;
    const int beg = (n == 0) ? 0 : offs[n - 1];
    const int end = offs[n];
    const unsigned short* h16 = (const unsigned short*)hptr;
    const float* hf = (const float*)hptr;
    float acc = 0.f;
    int k = beg;
    for (; k + 4 <= end; k += 4) {
        const int2 r0 = rec[k],     r1 = rec[k + 1];
        const int2 r2 = rec[k + 2], r3 = rec[k + 3];
        float v0, v1, v2, v3;
        if (BF16) {
            v0 = __uint_as_float((unsigned)h16[(size_t)r0.x * NDIM + lane] << 16);
            v1 = __uint_as_float((unsigned)h16[(size_t)r1.x * NDIM + lane] << 16);
            v2 = __uint_as_float((unsigned)h16[(size_t)r2.x * NDIM + lane] << 16);
            v3 = __uint_as_float((unsigned)h16[(size_t)r3.x * NDIM + lane] << 16);
        } else {
            v0 = hf[(size_t)r0.x * NDIM + lane];
            v1 = hf[(size_t)r1.x * NDIM + lane];
            v2 = hf[(size_t)r2.x * NDIM + lane];
            v3 = hf[(size_t)r3.x * NDIM + lane];
        }
        acc = fmaf(__int_as_float(r0.y), v0, acc);
        acc = fmaf(__int_as_float(r1.y), v1, acc);
        acc = fmaf(__int_as_float(r2.y), v2, acc);
        acc = fmaf(__int_as_float(r3.y), v3, acc);
    }
    for (; k < end; ++k) {
        const int2 r = rec[k];
        const float v = BF16
            ? __uint_as_float((unsigned)h16[(size_t)r.x * NDIM + lane] << 16)
            : hf[(size_t)r.x * NDIM + lane];
        acc = fmaf(__int_as_float(r.y), v, acc);
    }
    out[(size_t)n * NDIM + lane] = acc;
}

extern "C" void kernel_launch(void* const* d_in, const int* in_sizes, int n_in,
                              void* d_out, int out_size, void* d_ws, size_t ws_size,
                              hipStream_t stream) {
    const float* h   = (const float*)d_in[0];
    const float* pw  = (const float*)d_in[1];
    const float* nw  = (const float*)d_in[2];
    const int* edges = (const int*)d_in[3];
    float* out = (float*)d_out;

    const int n_nodes = in_sizes[0] / NDIM;
    const int n_edges = in_sizes[3] / 8;
    const size_t E = (size_t)n_edges, N = (size_t)n_nodes;

    const size_t szEx = E * 4, szRec = E * 8, szPv = E * 4;
    const size_t szH16 = N * NDIM * 2, szS12 = N * 8;
    const size_t szOffs = (N + 1) * 4, szRd = N * 4, szB = 1024;

    const size_t need_A = szEx + szRec + szPv + szH16 + szS12 + szOffs + szRd + szB;
    const size_t need_B = szEx + szRec + szH16 + szOffs + szRd + szB;
    const bool tierA = (ws_size >= need_A) && (n_nodes <= 65536);
    const bool tierB = !tierA && (ws_size >= need_B);

    char* p = (char*)d_ws;
    float* ex  = (float*)p; p += szEx;
    int2*  rec = (int2*)p;  p += szRec;
    unsigned* pvivj = nullptr;
    unsigned short* h16 = nullptr;
    float2* s12 = nullptr;
    if (tierA) {
        pvivj = (unsigned*)p; p += szPv;
        h16 = (unsigned short*)p; p += szH16;
        s12 = (float2*)p; p += szS12;
    } else if (tierB) {
        h16 = (unsigned short*)p; p += szH16;
    }
    int*   offs   = (int*)p;   p += szOffs;   // doubles as hist
    float* rdenom = (float*)p; p += szRd;
    int*   bsum   = (int*)p;   p += szB;

    hipMemsetAsync(offs, 0, szOffs, stream);

    const int eb = (n_edges + 255) / 256;
    const int nb = (n_nodes + 255) / 256;
    const int nw4 = (n_nodes + 3) / 4;

    if (tierA) {
        k_nodeprep<<<nw4, 256, 0, stream>>>(h, pw, nw, h16, s12, n_nodes);
        k0b_pack<<<eb, 256, 0, stream>>>(edges, pvivj, offs, n_edges);
        scan_blocks<<<nb, 256, 0, stream>>>(offs, bsum, n_nodes);
        scan_top<<<1, 256, 0, stream>>>(bsum, nb);
        scan_add<<<(n_nodes + 1 + 255) / 256, 256, 0, stream>>>(offs, bsum, n_nodes, n_edges);
        k1_fold<<<eb, 256, 0, stream>>>(pvivj, h16, s12, pw + 128, nw + 128, ex, n_edges);
        k2_denom<true><<<nb, 256, 0, stream>>>(pvivj, 1, ex, rdenom, n_edges, n_nodes);
        k3a_scatter<true><<<eb, 256, 0, stream>>>(pvivj, 1, ex, rdenom, offs, rec, n_edges);
        k3b_gather<true><<<nw4, 256, 0, stream>>>(rec, offs, h16, out, n_nodes);
    } else if (tierB) {
        const int n4 = (int)(N * NDIM / 4);
        k00_cvt<<<(n4 + 255) / 256, 256, 0, stream>>>(h, (unsigned int*)h16, n4);
        k1_full<true><<<eb, 256, 0, stream>>>(edges, h16, pw, nw, ex, offs, n_edges);
        scan_blocks<<<nb, 256, 0, stream>>>(offs, bsum, n_nodes);
        scan_top<<<1, 256, 0, stream>>>(bsum, nb);
        scan_add<<<(n_nodes + 1 + 255) / 256, 256, 0, stream>>>(offs, bsum, n_nodes, n_edges);
        k2_denom<false><<<nb, 256, 0, stream>>>(edges + 1, 8, ex, rdenom, n_edges, n_nodes);
        k3a_scatter<false><<<eb, 256, 0, stream>>>(edges + 1, 8, ex, rdenom, offs, rec, n_edges);
        k3b_gather<true><<<nw4, 256, 0, stream>>>(rec, offs, h16, out, n_nodes);
    } else {
        k1_full<false><<<eb, 256, 0, stream>>>(edges, h, pw, nw, ex, offs, n_edges);
        scan_blocks<<<nb, 256, 0, stream>>>(offs, bsum, n_nodes);
        scan_top<<<1, 256, 0, stream>>>(bsum, nb);
        scan_add<<<(n_nodes + 1 + 255) / 256, 256, 0, stream>>>(offs, bsum, n_nodes, n_edges);
        k2_denom<false><<<nb, 256, 0, stream>>>(edges + 1, 8, ex, rdenom, n_edges, n_nodes);
        k3a_scatter<false><<<eb, 256, 0, stream>>>(edges + 1, 8, ex, rdenom, offs, rec, n_edges);
        k3b_gather<false><<<nw4, 256, 0, stream>>>(rec, offs, h, out, n_nodes);
    }
}

// Round 7
// 338.308 us; speedup vs baseline: 1.0161x; 1.0161x over previous
//
#include <hip/hip_runtime.h>
#include <math.h>

#define NDIM 64

__device__ __forceinline__ unsigned bf16rne(unsigned u) {
    return (u + 0x7fffu + ((u >> 16) & 1u)) >> 16;
}

// ---------- nodeprep (tier A): wave per node -> h16 row + s12 scalars ----------
__global__ void __launch_bounds__(256)
k_nodeprep(const float* __restrict__ h,
           const float* __restrict__ pw, const float* __restrict__ nw,
           unsigned short* __restrict__ h16, float2* __restrict__ s12, int n_nodes) {
    const int lane = threadIdx.x & 63;
    const int n = blockIdx.x * 4 + (threadIdx.x >> 6);
    if (n >= n_nodes) return;
    const float a = h[(size_t)n * NDIM + lane];
    const float pa = fmaxf(a, 0.f), na = pa - a;
    float t1 = pa * pw[lane]      - na * nw[lane];
    float t2 = pa * pw[64 + lane] - na * nw[64 + lane];
    #pragma unroll
    for (int m = 32; m >= 1; m >>= 1) {
        t1 += __shfl_xor(t1, m, 64);
        t2 += __shfl_xor(t2, m, 64);
    }
    h16[(size_t)n * NDIM + lane] = (unsigned short)bf16rne(__float_as_uint(a));
    if (lane == 0) s12[n] = make_float2(t1, t2);
}

// ---------- k00 (tier B): h f32 -> bf16 ----------
__global__ void __launch_bounds__(256)
k00_cvt(const float* __restrict__ h, unsigned int* __restrict__ h16, int n4) {
    const int i = blockIdx.x * 256 + threadIdx.x;
    if (i >= n4) return;
    const float4 f = ((const float4*)h)[i];
    unsigned bx = bf16rne(__float_as_uint(f.x)), by = bf16rne(__float_as_uint(f.y));
    unsigned bz = bf16rne(__float_as_uint(f.z)), bw = bf16rne(__float_as_uint(f.w));
    ((uint2*)h16)[i] = make_uint2(bx | (by << 16), bz | (bw << 16));
}

// ---------- k0b (tier A): compact packed (vi | vj<<16) + vj histogram ----------
__global__ void __launch_bounds__(256)
k0b_pack(const int* __restrict__ edges, unsigned* __restrict__ pvivj,
         int* __restrict__ hist, int n_edges) {
    const int e = blockIdx.x * 256 + threadIdx.x;
    if (e >= n_edges) return;
    const int vi = edges[e * 8 + 1];
    const int vj = edges[e * 8 + 2];
    pvivj[e] = (unsigned)vi | ((unsigned)vj << 16);
    atomicAdd(&hist[vj], 1);
}

// ---------- single-block exclusive scan of hist[0..n-1]; data[n]=total ----------
__global__ void __launch_bounds__(256)
scan_single(int* __restrict__ data, int n) {
    __shared__ int partial[256];
    const int t = threadIdx.x;
    const int chunk = (n + 255) / 256;
    const int beg = t * chunk;
    const int end = min(beg + chunk, n);
    int s = 0;
    for (int i = beg; i < end; ++i) s += data[i];
    partial[t] = s;
    __syncthreads();
    int x = s;
    #pragma unroll
    for (int off = 1; off < 256; off <<= 1) {
        int add = (t >= off) ? partial[t - off] : 0;
        __syncthreads();
        x += add; partial[t] = x;
        __syncthreads();
    }
    int run = x - s;  // exclusive prefix of this chunk
    for (int i = beg; i < end; ++i) { const int v = data[i]; data[i] = run; run += v; }
    if (t == 255) data[n] = run;
}

// ---------- k1 fused (tier A): folded logit + ex store + 4B rec scatter ----------
__global__ void __launch_bounds__(256)
k1_fused(const unsigned* __restrict__ pvivj,
         const unsigned short* __restrict__ h16,
         const float2* __restrict__ s12,
         const float* __restrict__ w2p, const float* __restrict__ w2n,
         float* __restrict__ ex,
         int* __restrict__ offs,           // running cursors (post-scan)
         unsigned* __restrict__ rec,       // (vi<<16) | bf16(ex)
         int n_edges) {
    const int e = blockIdx.x * 256 + threadIdx.x;
    if (e >= n_edges) return;
    const unsigned v = pvivj[e];
    const int vi = (int)(v & 0xffffu), vj = (int)(v >> 16);
    const uint4* hi = (const uint4*)(h16 + (size_t)vi * NDIM);
    const uint4* hj = (const uint4*)(h16 + (size_t)vj * NDIM);
    float cp = 0.f, cn = 0.f;
    #pragma unroll
    for (int q = 0; q < 8; ++q) {
        const uint4 ua = hi[q];
        const uint4 ub = hj[q];
        const unsigned au[4] = {ua.x, ua.y, ua.z, ua.w};
        const unsigned bu[4] = {ub.x, ub.y, ub.z, ub.w};
        #pragma unroll
        for (int k = 0; k < 4; ++k) {
            const int d = q * 8 + k * 2;
            const float a0 = __uint_as_float(au[k] << 16);
            const float a1 = __uint_as_float(au[k] & 0xffff0000u);
            const float b0 = __uint_as_float(bu[k] << 16);
            const float b1 = __uint_as_float(bu[k] & 0xffff0000u);
            const float pa0 = fmaxf(a0, 0.f), na0 = pa0 - a0;
            const float pb0 = fmaxf(b0, 0.f), nb0 = pb0 - b0;
            const float pa1 = fmaxf(a1, 0.f), na1 = pa1 - a1;
            const float pb1 = fmaxf(b1, 0.f), nb1 = pb1 - b1;
            cp = fmaf(pa0 * pb0, w2p[d],     cp);
            cn = fmaf(na0 * nb0, w2n[d],     cn);
            cp = fmaf(pa1 * pb1, w2p[d + 1], cp);
            cn = fmaf(na1 * nb1, w2n[d + 1], cn);
        }
    }
    const float2 si = s12[vi];
    const float2 sj = s12[vj];
    const float exf = __expf(si.x + sj.y + cp - cn);
    ex[e] = exf;
    const int pos = atomicAdd(&offs[vj], 1);
    rec[pos] = ((unsigned)vi << 16) | bf16rne(__float_as_uint(exf));
}

__device__ __forceinline__ float edge_term(float a, float b,
                                           float w0, float w1, float w2,
                                           float w3, float w4, float w5) {
    const float pa = fmaxf(a, 0.f), na = pa - a;
    const float pb = fmaxf(b, 0.f), nb = pb - b;
    return pa * w0 + pb * w1 + (pa * pb) * w2
         - (na * w3 + nb * w4 + (na * nb) * w5);
}

// ---------- k1 (tier B/C): full math reading stride-8 edge table ----------
template <bool BF16>
__global__ void __launch_bounds__(256)
k1_full(const int* __restrict__ edges,
        const void* __restrict__ hptr,
        const float* __restrict__ pw,
        const float* __restrict__ nw,
        float* __restrict__ ex,
        int* __restrict__ hist,
        int n_edges) {
    const int e = blockIdx.x * 256 + threadIdx.x;
    if (e >= n_edges) return;
    const int vi = edges[e * 8 + 1];
    const int vj = edges[e * 8 + 2];
    float c = 0.f;
    if (BF16) {
        const unsigned short* h16 = (const unsigned short*)hptr;
        const uint4* hi = (const uint4*)(h16 + (size_t)vi * NDIM);
        const uint4* hj = (const uint4*)(h16 + (size_t)vj * NDIM);
        #pragma unroll 4
        for (int q = 0; q < 8; ++q) {
            const uint4 ua = hi[q];
            const uint4 ub = hj[q];
            const unsigned au[4] = {ua.x, ua.y, ua.z, ua.w};
            const unsigned bu[4] = {ub.x, ub.y, ub.z, ub.w};
            #pragma unroll
            for (int k = 0; k < 4; ++k) {
                const int d = q * 8 + k * 2;
                const float a0 = __uint_as_float(au[k] << 16);
                const float a1 = __uint_as_float(au[k] & 0xffff0000u);
                const float b0 = __uint_as_float(bu[k] << 16);
                const float b1 = __uint_as_float(bu[k] & 0xffff0000u);
                c += edge_term(a0, b0, pw[d], pw[64 + d], pw[128 + d],
                                       nw[d], nw[64 + d], nw[128 + d]);
                c += edge_term(a1, b1, pw[d + 1], pw[64 + d + 1], pw[128 + d + 1],
                                       nw[d + 1], nw[64 + d + 1], nw[128 + d + 1]);
            }
        }
    } else {
        const float* h = (const float*)hptr;
        const float4* hi = (const float4*)(h + (size_t)vi * NDIM);
        const float4* hj = (const float4*)(h + (size_t)vj * NDIM);
        #pragma unroll 4
        for (int q = 0; q < 16; ++q) {
            const float4 a = hi[q];
            const float4 b = hj[q];
            const int d = q * 4;
            c += edge_term(a.x, b.x, pw[d],     pw[64 + d],     pw[128 + d],
                                     nw[d],     nw[64 + d],     nw[128 + d]);
            c += edge_term(a.y, b.y, pw[d + 1], pw[64 + d + 1], pw[128 + d + 1],
                                     nw[d + 1], nw[64 + d + 1], nw[128 + d + 1]);
            c += edge_term(a.z, b.z, pw[d + 2], pw[64 + d + 2], pw[128 + d + 2],
                                     nw[d + 2], nw[64 + d + 2], nw[128 + d + 2]);
            c += edge_term(a.w, b.w, pw[d + 3], pw[64 + d + 3], pw[128 + d + 3],
                                     nw[d + 3], nw[64 + d + 3], nw[128 + d + 3]);
        }
    }
    ex[e] = __expf(c);
    atomicAdd(&hist[vj], 1);
}

// ---------- k2: thread per node, binary search sorted vi, rdenom ----------
template <bool PACKED>
__global__ void __launch_bounds__(256)
k2_denom(const void* __restrict__ viptr, int stride,
         const float* __restrict__ ex, float* __restrict__ rdenom,
         int n_edges, int n_nodes) {
    const int n = blockIdx.x * 256 + threadIdx.x;
    if (n >= n_nodes) return;
    const unsigned* pv = (const unsigned*)viptr;
    const int* va = (const int*)viptr;
    int lo = 0, hi = n_edges;
    while (lo < hi) {
        int mid = (lo + hi) >> 1;
        int v = PACKED ? (int)(pv[mid] & 0xffffu) : va[(size_t)mid * stride];
        if (v < n) lo = mid + 1; else hi = mid;
    }
    const int beg = lo;
    hi = n_edges;
    while (lo < hi) {
        int mid = (lo + hi) >> 1;
        int v = PACKED ? (int)(pv[mid] & 0xffffu) : va[(size_t)mid * stride];
        if (v < n + 1) lo = mid + 1; else hi = mid;
    }
    const int end = lo;
    float s = 0.f;
    for (int e = beg; e < end; ++e) s += ex[e];
    rdenom[n] = (end > beg) ? 1.f / s : 0.f;
}

// ---------- k3a (tier B/C): scatter 4B recs; atomic cursor on offs ----------
__global__ void __launch_bounds__(256)
k3a_scatter(const int* __restrict__ edges,
            const float* __restrict__ ex,
            int* __restrict__ offs, unsigned* __restrict__ rec, int n_edges) {
    const int e = blockIdx.x * 256 + threadIdx.x;
    if (e >= n_edges) return;
    const int vi = edges[(size_t)e * 8 + 1];
    const int vj = edges[(size_t)e * 8 + 2];
    const int pos = atomicAdd(&offs[vj], 1);
    rec[pos] = ((unsigned)vi << 16) | bf16rne(__float_as_uint(ex[e]));
}

// ---------- k3b: wave per node; rec=(vi<<16|bf16 ex); attn folded here ----------
template <bool BF16>
__global__ void __launch_bounds__(256)
k3b_gather(const unsigned* __restrict__ rec, const int* __restrict__ offs,
           const float* __restrict__ rdenom,
           const void* __restrict__ hptr, float* __restrict__ out, int n_nodes) {
    const int lane = threadIdx.x & 63;
    const int n = blockIdx.x * 4 + (threadIdx.x >> 6);
    if (n >= n_nodes) return;
    const int beg = (n == 0) ? 0 : offs[n - 1];
    const int end = offs[n];
    const unsigned short* h16 = (const unsigned short*)hptr;
    const float* hf = (const float*)hptr;
    float acc = 0.f;
    int k = beg;
    for (; k + 4 <= end; k += 4) {
        const unsigned r0 = rec[k],     r1 = rec[k + 1];
        const unsigned r2 = rec[k + 2], r3 = rec[k + 3];
        const int i0 = (int)(r0 >> 16), i1 = (int)(r1 >> 16);
        const int i2 = (int)(r2 >> 16), i3 = (int)(r3 >> 16);
        const float w0 = __uint_as_float(r0 << 16) * rdenom[i0];
        const float w1 = __uint_as_float(r1 << 16) * rdenom[i1];
        const float w2 = __uint_as_float(r2 << 16) * rdenom[i2];
        const float w3 = __uint_as_float(r3 << 16) * rdenom[i3];
        float v0, v1, v2, v3;
        if (BF16) {
            v0 = __uint_as_float((unsigned)h16[(size_t)i0 * NDIM + lane] << 16);
            v1 = __uint_as_float((unsigned)h16[(size_t)i1 * NDIM + lane] << 16);
            v2 = __uint_as_float((unsigned)h16[(size_t)i2 * NDIM + lane] << 16);
            v3 = __uint_as_float((unsigned)h16[(size_t)i3 * NDIM + lane] << 16);
        } else {
            v0 = hf[(size_t)i0 * NDIM + lane];
            v1 = hf[(size_t)i1 * NDIM + lane];
            v2 = hf[(size_t)i2 * NDIM + lane];
            v3 = hf[(size_t)i3 * NDIM + lane];
        }
        acc = fmaf(w0, v0, acc);
        acc = fmaf(w1, v1, acc);
        acc = fmaf(w2, v2, acc);
        acc = fmaf(w3, v3, acc);
    }
    for (; k < end; ++k) {
        const unsigned r = rec[k];
        const int i = (int)(r >> 16);
        const float w = __uint_as_float(r << 16) * rdenom[i];
        const float v = BF16
            ? __uint_as_float((unsigned)h16[(size_t)i * NDIM + lane] << 16)
            : hf[(size_t)i * NDIM + lane];
        acc = fmaf(w, v, acc);
    }
    out[(size_t)n * NDIM + lane] = acc;
}

extern "C" void kernel_launch(void* const* d_in, const int* in_sizes, int n_in,
                              void* d_out, int out_size, void* d_ws, size_t ws_size,
                              hipStream_t stream) {
    const float* h   = (const float*)d_in[0];
    const float* pw  = (const float*)d_in[1];
    const float* nw  = (const float*)d_in[2];
    const int* edges = (const int*)d_in[3];
    float* out = (float*)d_out;

    const int n_nodes = in_sizes[0] / NDIM;
    const int n_edges = in_sizes[3] / 8;
    const size_t E = (size_t)n_edges, N = (size_t)n_nodes;

    const size_t szEx = E * 4, szRec = E * 4, szPv = E * 4;
    const size_t szH16 = N * NDIM * 2, szS12 = N * 8;
    const size_t szOffs = (N + 1) * 4, szRd = N * 4;

    const size_t need_A = szEx + szRec + szPv + szH16 + szS12 + szOffs + szRd;
    const size_t need_B = szEx + szRec + szH16 + szOffs + szRd;
    const bool tierA = (ws_size >= need_A) && (n_nodes <= 65536);
    const bool tierB = !tierA && (ws_size >= need_B);

    char* p = (char*)d_ws;
    float*    ex  = (float*)p;    p += szEx;
    unsigned* rec = (unsigned*)p; p += szRec;
    unsigned* pvivj = nullptr;
    unsigned short* h16 = nullptr;
    float2* s12 = nullptr;
    if (tierA) {
        pvivj = (unsigned*)p; p += szPv;
        h16 = (unsigned short*)p; p += szH16;
        s12 = (float2*)p; p += szS12;
    } else if (tierB) {
        h16 = (unsigned short*)p; p += szH16;
    }
    int*   offs   = (int*)p;   p += szOffs;   // doubles as hist, then cursors
    float* rdenom = (float*)p; p += szRd;

    hipMemsetAsync(offs, 0, szOffs, stream);

    const int eb = (n_edges + 255) / 256;
    const int nb = (n_nodes + 255) / 256;
    const int nw4 = (n_nodes + 3) / 4;

    if (tierA) {
        k_nodeprep<<<nw4, 256, 0, stream>>>(h, pw, nw, h16, s12, n_nodes);
        k0b_pack<<<eb, 256, 0, stream>>>(edges, pvivj, offs, n_edges);
        scan_single<<<1, 256, 0, stream>>>(offs, n_nodes);
        k1_fused<<<eb, 256, 0, stream>>>(pvivj, h16, s12, pw + 128, nw + 128, ex, offs, rec, n_edges);
        k2_denom<true><<<nb, 256, 0, stream>>>(pvivj, 1, ex, rdenom, n_edges, n_nodes);
        k3b_gather<true><<<nw4, 256, 0, stream>>>(rec, offs, rdenom, h16, out, n_nodes);
    } else if (tierB) {
        const int n4 = (int)(N * NDIM / 4);
        k00_cvt<<<(n4 + 255) / 256, 256, 0, stream>>>(h, (unsigned int*)h16, n4);
        k1_full<true><<<eb, 256, 0, stream>>>(edges, h16, pw, nw, ex, offs, n_edges);
        scan_single<<<1, 256, 0, stream>>>(offs, n_nodes);
        k2_denom<false><<<nb, 256, 0, stream>>>(edges + 1, 8, ex, rdenom, n_edges, n_nodes);
        k3a_scatter<<<eb, 256, 0, stream>>>(edges, ex, offs, rec, n_edges);
        k3b_gather<true><<<nw4, 256, 0, stream>>>(rec, offs, rdenom, h16, out, n_nodes);
    } else {
        k1_full<false><<<eb, 256, 0, stream>>>(edges, h, pw, nw, ex, offs, n_edges);
        scan_single<<<1, 256, 0, stream>>>(offs, n_nodes);
        k2_denom<false><<<nb, 256, 0, stream>>>(edges + 1, 8, ex, rdenom, n_edges, n_nodes);
        k3a_scatter<<<eb, 256, 0, stream>>>(edges, ex, offs, rec, n_edges);
        k3b_gather<false><<<nw4, 256, 0, stream>>>(rec, offs, rdenom, h, out, n_nodes);
    }
}

// Round 8
// 273.794 us; speedup vs baseline: 1.2556x; 1.2356x over previous
//
#include <hip/hip_runtime.h>
#include <math.h>

#define NDIM 64
#define NGRP 8

__device__ __forceinline__ unsigned bf16rne(unsigned u) {
    return (u + 0x7fffu + ((u >> 16) & 1u)) >> 16;
}

// ---------- fused nodeprep + pack (tier A) ----------
// blocks [0, node_blocks): wave-per-node -> h16 row + s12 scalars
// blocks [node_blocks, ..): thread-per-edge -> pvivj pack + per-(g,vj) hist
__global__ void __launch_bounds__(256)
k_prep_pack(const float* __restrict__ h,
            const float* __restrict__ pw, const float* __restrict__ nw,
            unsigned short* __restrict__ h16, float2* __restrict__ s12,
            const int* __restrict__ edges, unsigned* __restrict__ pvivj,
            int* __restrict__ hist2,
            int n_nodes, int n_edges, int node_blocks) {
    if ((int)blockIdx.x < node_blocks) {
        const int lane = threadIdx.x & 63;
        const int n = blockIdx.x * 4 + (threadIdx.x >> 6);
        if (n >= n_nodes) return;
        const float a = h[(size_t)n * NDIM + lane];
        const float pa = fmaxf(a, 0.f), na = pa - a;
        float t1 = pa * pw[lane]      - na * nw[lane];
        float t2 = pa * pw[64 + lane] - na * nw[64 + lane];
        #pragma unroll
        for (int m = 32; m >= 1; m >>= 1) {
            t1 += __shfl_xor(t1, m, 64);
            t2 += __shfl_xor(t2, m, 64);
        }
        h16[(size_t)n * NDIM + lane] = (unsigned short)bf16rne(__float_as_uint(a));
        if (lane == 0) s12[n] = make_float2(t1, t2);
    } else {
        const int e = ((int)blockIdx.x - node_blocks) * 256 + threadIdx.x;
        if (e >= n_edges) return;
        const int vi = edges[(size_t)e * 8 + 1];
        const int vj = edges[(size_t)e * 8 + 2];
        pvivj[e] = (unsigned)vi | ((unsigned)vj << 16);
        const int g = (e >> 8) & (NGRP - 1);      // = k1's blockIdx % NGRP
        atomicAdd(&hist2[g * n_nodes + vj], 1);
    }
}

// ---------- 3-level exclusive scan over n entries ----------
__global__ void __launch_bounds__(256)
scan_blocks(int* __restrict__ data, int* __restrict__ bsum, int n) {
    __shared__ int sm[256];
    const int t = threadIdx.x;
    const int i = blockIdx.x * 256 + t;
    int v = (i < n) ? data[i] : 0;
    sm[t] = v;
    __syncthreads();
    int x = v;
    #pragma unroll
    for (int off = 1; off < 256; off <<= 1) {
        int add = (t >= off) ? sm[t - off] : 0;
        __syncthreads();
        x += add; sm[t] = x;
        __syncthreads();
    }
    if (i < n) data[i] = x - v;
    if (t == 255) bsum[blockIdx.x] = x;
}

__global__ void __launch_bounds__(256)
scan_top(int* __restrict__ bsum, int nb) {   // nb <= 256*16
    __shared__ int sm[256];
    const int t = threadIdx.x;
    const int chunk = (nb + 255) / 256;
    const int beg = t * chunk, end = min(beg + chunk, nb);
    int s = 0;
    for (int i = beg; i < end; ++i) s += bsum[i];
    sm[t] = s;
    __syncthreads();
    int x = s;
    #pragma unroll
    for (int off = 1; off < 256; off <<= 1) {
        int add = (t >= off) ? sm[t - off] : 0;
        __syncthreads();
        x += add; sm[t] = x;
        __syncthreads();
    }
    int run = x - s;
    for (int i = beg; i < end; ++i) { const int v = bsum[i]; bsum[i] = run; run += v; }
}

__global__ void __launch_bounds__(256)
scan_add(int* __restrict__ data, const int* __restrict__ bsum, int n, int total) {
    const int i = blockIdx.x * 256 + threadIdx.x;
    if (i < n) data[i] += bsum[blockIdx.x];
    else if (i == n) data[i] = total;
}

// ---------- k1 (tier A): folded logit + segmented denom + XCD-local scatter ----------
__global__ void __launch_bounds__(256)
k1_fused8(const unsigned* __restrict__ pvivj,
          const unsigned short* __restrict__ h16,
          const float2* __restrict__ s12,
          const float* __restrict__ w2p, const float* __restrict__ w2n,
          float* __restrict__ denom,
          int* __restrict__ offs2,          // per-(g,vj) running cursors
          unsigned* __restrict__ rec,       // (vi<<16) | bf16(ex)
          int n_nodes, int n_edges) {
    const int e = blockIdx.x * 256 + threadIdx.x;
    const int lane = threadIdx.x & 63;
    const int ee = min(e, n_edges - 1);
    const unsigned v = pvivj[ee];
    const int vi = (int)(v & 0xffffu), vj = (int)(v >> 16);
    const uint4* hi = (const uint4*)(h16 + (size_t)vi * NDIM);
    const uint4* hj = (const uint4*)(h16 + (size_t)vj * NDIM);
    float cp = 0.f, cn = 0.f;
    #pragma unroll
    for (int q = 0; q < 8; ++q) {
        const uint4 ua = hi[q];
        const uint4 ub = hj[q];
        const unsigned au[4] = {ua.x, ua.y, ua.z, ua.w};
        const unsigned bu[4] = {ub.x, ub.y, ub.z, ub.w};
        #pragma unroll
        for (int k = 0; k < 4; ++k) {
            const int d = q * 8 + k * 2;
            const float a0 = __uint_as_float(au[k] << 16);
            const float a1 = __uint_as_float(au[k] & 0xffff0000u);
            const float b0 = __uint_as_float(bu[k] << 16);
            const float b1 = __uint_as_float(bu[k] & 0xffff0000u);
            const float pa0 = fmaxf(a0, 0.f), na0 = pa0 - a0;
            const float pb0 = fmaxf(b0, 0.f), nb0 = pb0 - b0;
            const float pa1 = fmaxf(a1, 0.f), na1 = pa1 - a1;
            const float pb1 = fmaxf(b1, 0.f), nb1 = pb1 - b1;
            cp = fmaf(pa0 * pb0, w2p[d],     cp);
            cn = fmaf(na0 * nb0, w2n[d],     cn);
            cp = fmaf(pa1 * pb1, w2p[d + 1], cp);
            cn = fmaf(na1 * nb1, w2n[d + 1], cn);
        }
    }
    const float2 si = s12[vi];
    const float2 sj = s12[vj];
    const float exf = (e < n_edges) ? __expf(si.x + sj.y + cp - cn) : 0.f;

    // wave-level segmented inclusive scan of exf over equal-vi runs (vi sorted)
    float s = exf;
    #pragma unroll
    for (int o = 1; o < 64; o <<= 1) {
        const float pv = __shfl_up(s, o, 64);
        const int   pi = __shfl_up(vi, o, 64);
        if (lane >= o && pi == vi) s += pv;
    }
    const int nvi = __shfl_down(vi, 1, 64);
    if (lane == 63 || nvi != vi) atomicAdd(&denom[vi], s);  // fire-and-forget

    if (e < n_edges) {
        const int g = blockIdx.x & (NGRP - 1);
        const int pos = atomicAdd(&offs2[g * n_nodes + vj], 1);
        rec[pos] = ((unsigned)vi << 16) | bf16rne(__float_as_uint(exf));
    }
}

// ---------- rcp: denom -> rdenom in place ----------
__global__ void __launch_bounds__(256)
k_rcp(float* __restrict__ denom, int n) {
    const int i = blockIdx.x * 256 + threadIdx.x;
    if (i < n) {
        const float d = denom[i];
        denom[i] = (d > 0.f) ? 1.f / d : 0.f;
    }
}

// ---------- gather (tier A): wave per node, 8 sub-segments ----------
__global__ void __launch_bounds__(256)
k3b_gather8(const unsigned* __restrict__ rec, const int* __restrict__ offs2,
            const float* __restrict__ rdenom,
            const unsigned short* __restrict__ h16,
            float* __restrict__ out, int n_nodes) {
    const int lane = threadIdx.x & 63;
    const int n = blockIdx.x * 4 + (threadIdx.x >> 6);
    if (n >= n_nodes) return;
    int begs[NGRP], ends[NGRP];
    #pragma unroll
    for (int g = 0; g < NGRP; ++g) {
        const int i = g * n_nodes + n;
        begs[g] = (i == 0) ? 0 : offs2[i - 1];
        ends[g] = offs2[i];
    }
    float acc = 0.f;
    #pragma unroll
    for (int g = 0; g < NGRP; ++g) {
        int k = begs[g];
        const int end = ends[g];
        for (; k + 2 <= end; k += 2) {
            const unsigned r0 = rec[k], r1 = rec[k + 1];
            const int i0 = (int)(r0 >> 16), i1 = (int)(r1 >> 16);
            const float w0 = __uint_as_float(r0 << 16) * rdenom[i0];
            const float w1 = __uint_as_float(r1 << 16) * rdenom[i1];
            acc = fmaf(w0, __uint_as_float((unsigned)h16[(size_t)i0 * NDIM + lane] << 16), acc);
            acc = fmaf(w1, __uint_as_float((unsigned)h16[(size_t)i1 * NDIM + lane] << 16), acc);
        }
        if (k < end) {
            const unsigned r = rec[k];
            const int i0 = (int)(r >> 16);
            acc = fmaf(__uint_as_float(r << 16) * rdenom[i0],
                       __uint_as_float((unsigned)h16[(size_t)i0 * NDIM + lane] << 16), acc);
        }
    }
    out[(size_t)n * NDIM + lane] = acc;
}

// ================= tier C fallback (small ws; fp32, proven kernels) =================
__device__ __forceinline__ float edge_term(float a, float b,
                                           float w0, float w1, float w2,
                                           float w3, float w4, float w5) {
    const float pa = fmaxf(a, 0.f), na = pa - a;
    const float pb = fmaxf(b, 0.f), nb = pb - b;
    return pa * w0 + pb * w1 + (pa * pb) * w2
         - (na * w3 + nb * w4 + (na * nb) * w5);
}

__global__ void __launch_bounds__(256)
k1_full_c(const int* __restrict__ edges, const float* __restrict__ h,
          const float* __restrict__ pw, const float* __restrict__ nw,
          float* __restrict__ ex, int* __restrict__ hist, int n_edges) {
    const int e = blockIdx.x * 256 + threadIdx.x;
    if (e >= n_edges) return;
    const int vi = edges[(size_t)e * 8 + 1];
    const int vj = edges[(size_t)e * 8 + 2];
    const float4* hi = (const float4*)(h + (size_t)vi * NDIM);
    const float4* hj = (const float4*)(h + (size_t)vj * NDIM);
    float c = 0.f;
    #pragma unroll 4
    for (int q = 0; q < 16; ++q) {
        const float4 a = hi[q];
        const float4 b = hj[q];
        const int d = q * 4;
        c += edge_term(a.x, b.x, pw[d],     pw[64 + d],     pw[128 + d],
                                 nw[d],     nw[64 + d],     nw[128 + d]);
        c += edge_term(a.y, b.y, pw[d + 1], pw[64 + d + 1], pw[128 + d + 1],
                                 nw[d + 1], nw[64 + d + 1], nw[128 + d + 1]);
        c += edge_term(a.z, b.z, pw[d + 2], pw[64 + d + 2], pw[128 + d + 2],
                                 nw[d + 2], nw[64 + d + 2], nw[128 + d + 2]);
        c += edge_term(a.w, b.w, pw[d + 3], pw[64 + d + 3], pw[128 + d + 3],
                                 nw[d + 3], nw[64 + d + 3], nw[128 + d + 3]);
    }
    ex[e] = __expf(c);
    atomicAdd(&hist[vj], 1);
}

__global__ void __launch_bounds__(256)
k2_denom_c(const int* __restrict__ edges, const float* __restrict__ ex,
           float* __restrict__ rdenom, int n_edges, int n_nodes) {
    const int n = blockIdx.x * 256 + threadIdx.x;
    if (n >= n_nodes) return;
    int lo = 0, hi = n_edges;
    while (lo < hi) { int mid = (lo + hi) >> 1; if (edges[(size_t)mid * 8 + 1] < n) lo = mid + 1; else hi = mid; }
    const int beg = lo;
    hi = n_edges;
    while (lo < hi) { int mid = (lo + hi) >> 1; if (edges[(size_t)mid * 8 + 1] < n + 1) lo = mid + 1; else hi = mid; }
    const int end = lo;
    float s = 0.f;
    for (int e = beg; e < end; ++e) s += ex[e];
    rdenom[n] = (end > beg) ? 1.f / s : 0.f;
}

__global__ void __launch_bounds__(256)
k3a_scatter_c(const int* __restrict__ edges, const float* __restrict__ ex,
              int* __restrict__ offs, unsigned* __restrict__ rec, int n_edges) {
    const int e = blockIdx.x * 256 + threadIdx.x;
    if (e >= n_edges) return;
    const int vi = edges[(size_t)e * 8 + 1];
    const int vj = edges[(size_t)e * 8 + 2];
    const int pos = atomicAdd(&offs[vj], 1);
    rec[pos] = ((unsigned)vi << 16) | bf16rne(__float_as_uint(ex[e]));
}

__global__ void __launch_bounds__(256)
k3b_gather_c(const unsigned* __restrict__ rec, const int* __restrict__ offs,
             const float* __restrict__ rdenom, const float* __restrict__ h,
             float* __restrict__ out, int n_nodes) {
    const int lane = threadIdx.x & 63;
    const int n = blockIdx.x * 4 + (threadIdx.x >> 6);
    if (n >= n_nodes) return;
    const int beg = (n == 0) ? 0 : offs[n - 1];
    const int end = offs[n];
    float acc = 0.f;
    for (int k = beg; k < end; ++k) {
        const unsigned r = rec[k];
        const int i = (int)(r >> 16);
        acc = fmaf(__uint_as_float(r << 16) * rdenom[i], h[(size_t)i * NDIM + lane], acc);
    }
    out[(size_t)n * NDIM + lane] = acc;
}

extern "C" void kernel_launch(void* const* d_in, const int* in_sizes, int n_in,
                              void* d_out, int out_size, void* d_ws, size_t ws_size,
                              hipStream_t stream) {
    const float* h   = (const float*)d_in[0];
    const float* pw  = (const float*)d_in[1];
    const float* nw  = (const float*)d_in[2];
    const int* edges = (const int*)d_in[3];
    float* out = (float*)d_out;

    const int n_nodes = in_sizes[0] / NDIM;
    const int n_edges = in_sizes[3] / 8;
    const size_t E = (size_t)n_edges, N = (size_t)n_nodes;

    const size_t szPv = E * 4, szRec = E * 4, szH16 = N * NDIM * 2, szS12 = N * 8;
    const size_t szOffs2 = ((size_t)NGRP * N + 1) * 4, szDen = N * 4, szB = 16384;
    const size_t need_A = szPv + szRec + szH16 + szS12 + szOffs2 + szDen + szB;
    const bool tierA = (ws_size >= need_A) && (n_nodes <= 65536);

    const int eb  = (n_edges + 255) / 256;
    const int nbN = (n_nodes + 255) / 256;
    const int nw4 = (n_nodes + 3) / 4;

    if (tierA) {
        char* p = (char*)d_ws;
        unsigned* pvivj = (unsigned*)p;       p += szPv;
        unsigned* rec   = (unsigned*)p;       p += szRec;
        unsigned short* h16 = (unsigned short*)p; p += szH16;
        float2* s12   = (float2*)p;           p += szS12;
        int*    offs2 = (int*)p;              p += szOffs2;  // hist2 -> offsets -> cursors
        float*  denom = (float*)p;            p += szDen;    // -> rdenom
        int*    bsum  = (int*)p;              p += szB;

        // offs2 and denom contiguous -> one memset
        hipMemsetAsync(offs2, 0, szOffs2 + szDen, stream);

        k_prep_pack<<<nw4 + eb, 256, 0, stream>>>(h, pw, nw, h16, s12,
                                                  edges, pvivj, offs2,
                                                  n_nodes, n_edges, nw4);
        const int n8 = NGRP * n_nodes;
        const int nb8 = (n8 + 255) / 256;
        scan_blocks<<<nb8, 256, 0, stream>>>(offs2, bsum, n8);
        scan_top<<<1, 256, 0, stream>>>(bsum, nb8);
        scan_add<<<(n8 + 1 + 255) / 256, 256, 0, stream>>>(offs2, bsum, n8, n_edges);

        k1_fused8<<<eb, 256, 0, stream>>>(pvivj, h16, s12, pw + 128, nw + 128,
                                          denom, offs2, rec, n_nodes, n_edges);
        k_rcp<<<nbN, 256, 0, stream>>>(denom, n_nodes);
        k3b_gather8<<<nw4, 256, 0, stream>>>(rec, offs2, denom, h16, out, n_nodes);
    } else {
        char* p = (char*)d_ws;
        float*    ex  = (float*)p;    p += E * 4;
        unsigned* rec = (unsigned*)p; p += E * 4;
        int*   offs   = (int*)p;      p += (N + 1) * 4;
        float* rdenom = (float*)p;    p += N * 4;
        int*   bsum   = (int*)p;      p += 16384;

        hipMemsetAsync(offs, 0, (N + 1) * 4, stream);
        k1_full_c<<<eb, 256, 0, stream>>>(edges, h, pw, nw, ex, offs, n_edges);
        const int nbn = (n_nodes + 255) / 256;
        scan_blocks<<<nbn, 256, 0, stream>>>(offs, bsum, n_nodes);
        scan_top<<<1, 256, 0, stream>>>(bsum, nbn);
        scan_add<<<(n_nodes + 1 + 255) / 256, 256, 0, stream>>>(offs, bsum, n_nodes, n_edges);
        k2_denom_c<<<nbn, 256, 0, stream>>>(edges, ex, rdenom, n_edges, n_nodes);
        k3a_scatter_c<<<eb, 256, 0, stream>>>(edges, ex, offs, rec, n_edges);
        k3b_gather_c<<<nw4, 256, 0, stream>>>(rec, offs, rdenom, h, out, n_nodes);
    }
}